// Round 2
// baseline (700.981 us; speedup 1.0000x reference)
//
#include <hip/hip_runtime.h>
#include <math.h>

#define HH 224
#define WW 224
#define OH 112
#define OW 112
#define NCH 1024
#define YPITCH 225

// LrT[m][p]  (m in [0,224), p in [0,112)) : transposed so staging loads are contiguous.
__global__ void lrt_init_kernel(float* __restrict__ lrt) {
    int idx = blockIdx.x * blockDim.x + threadIdx.x;
    if (idx >= HH * OH) return;
    int m = idx / OH;
    int p = idx % OH;
    float val = 0.0f;
    if ((m & 1) == 0) {
        val = (m == 2 * p) ? 0.5f : 0.0f;
    } else {
        int j = m >> 1;
        int r = 2 * p - m;                       // odd
        float a = (float)M_PI * (float)r * (1.0f / 224.0f);
        float sg = ((p - j) & 1) ? 1.0f : -1.0f; // sigma = -(-1)^(p-j)
        val = sg * (cosf(a) / sinf(a)) * (1.0f / 224.0f);
    }
    lrt[m * OH + p] = val;
}

__launch_bounds__(512)
__global__ void flc_main_kernel(const float* __restrict__ x,
                                const float* __restrict__ lrt,
                                float* __restrict__ out) {
    __shared__ float Ybuf[OH * YPITCH];   // 100800 B, Y then reused as output tile
    __shared__ float xbuf[8 * WW];        // 7168 B
    __shared__ float lbuf[8 * OH];        // 3584 B
    __shared__ float wsum[8];
    __shared__ float s_sh;

    const int c = blockIdx.x;
    const int t = threadIdx.x;
    const float* __restrict__ xc = x + (size_t)c * (HH * WW);

    // ---- rank-1 correction scalar: s = (1/224^2) sum_{j,k} (-1)^(j+k) x[2j+1][2k+1]
    float part = 0.0f;
    for (int idx = t; idx < OH * OW; idx += 512) {
        int j = idx / OW, k = idx % OW;
        float v = xc[(2 * j + 1) * WW + (2 * k + 1)];
        part += ((j + k) & 1) ? -v : v;
    }
    #pragma unroll
    for (int off = 32; off > 0; off >>= 1)
        part += __shfl_down(part, off, 64);
    if ((t & 63) == 0) wsum[t >> 6] = part;
    __syncthreads();
    if (t == 0) {
        float ssum = 0.0f;
        #pragma unroll
        for (int w = 0; w < 8; ++w) ssum += wsum[w];
        s_sh = ssum * (1.0f / (224.0f * 224.0f));
    }

    // ---- Phase A: Y[p][n] = sum_m Lr[p][m] * X[m][n]
    const int ptg = t & 15;   // p = ptg + 16*i, i<7
    const int nt  = t >> 4;   // n = nt*7 + j,  j<7   (nt < 32)
    float acc[7][7];
    #pragma unroll
    for (int i = 0; i < 7; ++i)
        #pragma unroll
        for (int j = 0; j < 7; ++j) acc[i][j] = 0.0f;

    for (int m0 = 0; m0 < HH; m0 += 8) {
        if (t < 448) {
            *reinterpret_cast<float4*>(&xbuf[t * 4]) =
                *reinterpret_cast<const float4*>(xc + m0 * WW + t * 4);
        } else {
            int tt = t - 448;  // 64 stagers for lbuf: 224 float4s
            #pragma unroll
            for (int k = 0; k < 4; ++k) {
                int i4 = tt + 64 * k;
                if (i4 < 224) {
                    *reinterpret_cast<float4*>(&lbuf[i4 * 4]) =
                        *reinterpret_cast<const float4*>(lrt + m0 * OH + i4 * 4);
                }
            }
        }
        __syncthreads();
        #pragma unroll
        for (int mm = 0; mm < 8; ++mm) {
            float lr[7], xv[7];
            #pragma unroll
            for (int i = 0; i < 7; ++i) lr[i] = lbuf[mm * OH + ptg + 16 * i];
            #pragma unroll
            for (int j = 0; j < 7; ++j) xv[j] = xbuf[mm * WW + nt * 7 + j];
            #pragma unroll
            for (int i = 0; i < 7; ++i)
                #pragma unroll
                for (int j = 0; j < 7; ++j)
                    acc[i][j] = fmaf(lr[i], xv[j], acc[i][j]);
        }
        __syncthreads();
    }
    #pragma unroll
    for (int i = 0; i < 7; ++i)
        #pragma unroll
        for (int j = 0; j < 7; ++j)
            Ybuf[(ptg + 16 * i) * YPITCH + nt * 7 + j] = acc[i][j];
    __syncthreads();

    // ---- Phase B: out[p][q] = sum_n Y[p][n] * Lr[q][n]  - (-1)^(p+q) * s
    const int ptB = t & 15;   // p = ptB + 16*i, i<7
    const int qt  = t >> 4;   // q = qt*4 + j,  j<4  (active qt<28)
    float accB[7][4];
    #pragma unroll
    for (int i = 0; i < 7; ++i)
        #pragma unroll
        for (int j = 0; j < 4; ++j) accB[i][j] = 0.0f;

    for (int n0 = 0; n0 < WW; n0 += 8) {
        if (t < 224) {
            *reinterpret_cast<float4*>(&lbuf[t * 4]) =
                *reinterpret_cast<const float4*>(lrt + n0 * OH + t * 4);
        }
        __syncthreads();
        if (qt < 28) {
            #pragma unroll
            for (int nn = 0; nn < 8; ++nn) {
                int n = n0 + nn;
                float yv[7], lq[4];
                #pragma unroll
                for (int i = 0; i < 7; ++i) yv[i] = Ybuf[(ptB + 16 * i) * YPITCH + n];
                #pragma unroll
                for (int j = 0; j < 4; ++j) lq[j] = lbuf[nn * OH + qt * 4 + j];
                #pragma unroll
                for (int i = 0; i < 7; ++i)
                    #pragma unroll
                    for (int j = 0; j < 4; ++j)
                        accB[i][j] = fmaf(yv[i], lq[j], accB[i][j]);
            }
        }
        __syncthreads();
    }

    // ---- epilogue: apply rank-1 correction, stash tile in LDS, coalesced store
    const float s = s_sh;
    if (qt < 28) {
        #pragma unroll
        for (int i = 0; i < 7; ++i) {
            #pragma unroll
            for (int j = 0; j < 4; ++j) {
                int p = ptB + 16 * i;
                int q = qt * 4 + j;
                float v = accB[i][j] - (((p + q) & 1) ? -s : s);
                Ybuf[p * YPITCH + q] = v;
            }
        }
    }
    __syncthreads();
    float* __restrict__ oc = out + (size_t)c * (OH * OW);
    for (int idx = t; idx < OH * OW; idx += 512) {
        oc[idx] = Ybuf[(idx / OW) * YPITCH + (idx % OW)];
    }
}

extern "C" void kernel_launch(void* const* d_in, const int* in_sizes, int n_in,
                              void* d_out, int out_size, void* d_ws, size_t ws_size,
                              hipStream_t stream) {
    const float* x = (const float*)d_in[0];
    float* out = (float*)d_out;
    float* lrt = (float*)d_ws;   // 224*112*4 = 100352 bytes

    hipLaunchKernelGGL(lrt_init_kernel, dim3((HH * OH + 255) / 256), dim3(256), 0, stream, lrt);
    hipLaunchKernelGGL(flc_main_kernel, dim3(NCH), dim3(512), 0, stream, x, lrt, out);
}

// Round 3
// 363.417 us; speedup vs baseline: 1.9289x; 1.9289x over previous
//
#include <hip/hip_runtime.h>
#include <math.h>

#define HH 224
#define WW 224
#define OH 112
#define OW 112
#define NCH 1024
#define YP 232   // y_s pitch (bf16 elems): 16B-aligned rows, good bank spread

typedef __attribute__((ext_vector_type(8))) short s16x8;
typedef __attribute__((ext_vector_type(4))) float f32x4;

static __device__ __host__ __forceinline__ unsigned short f2bf(float f) {
    union { float f; unsigned int u; } v; v.f = f;
    unsigned int r = (v.u + 0x7FFFu + ((v.u >> 16) & 1u)) >> 16;  // RNE
    return (unsigned short)r;
}

// Lr bf16 ROW-major [p=112][m=224] (A-operand layout: row p, contiguous k=m)
__global__ void lr_init_kernel(unsigned short* __restrict__ lrbf) {
    int idx = blockIdx.x * blockDim.x + threadIdx.x;
    if (idx >= OH * HH) return;
    int p = idx / HH;
    int m = idx % HH;
    float val = 0.0f;
    if ((m & 1) == 0) {
        val = (m == 2 * p) ? 0.5f : 0.0f;
    } else {
        int j = m >> 1;
        int r = 2 * p - m;                       // odd
        float a = (float)M_PI * (float)r * (1.0f / 224.0f);
        float sg = ((p - j) & 1) ? 1.0f : -1.0f; // sigma = -(-1)^(p-j)
        val = sg * (cosf(a) / sinf(a)) * (1.0f / 224.0f);
    }
    lrbf[p * HH + m] = f2bf(val);
}

__launch_bounds__(448, 4)
__global__ void flc_mfma_kernel(const float* __restrict__ x,
                                const unsigned short* __restrict__ lrbf,
                                float* __restrict__ out) {
    __shared__ float x_s[32 * WW];            // 28672 B, linear (global_load_lds dest)
    __shared__ unsigned short y_s[OH * YP];   // 51968 B
    __shared__ float wsum[7];

    const int c = blockIdx.x;
    const int t = threadIdx.x;
    const int w = t >> 6;      // wave 0..6
    const int l = t & 63;
    const int lr16 = l & 15;
    const int g = l >> 4;      // 0..3

    const float* __restrict__ xc = x + (size_t)c * (HH * WW);

    f32x4 accA[7][2];
    #pragma unroll
    for (int i = 0; i < 7; ++i) {
        accA[i][0] = f32x4{0.f, 0.f, 0.f, 0.f};
        accA[i][1] = f32x4{0.f, 0.f, 0.f, 0.f};
    }
    float spart = 0.0f;

    // ---------------- Phase A: Y = Lr * X  (K = m, 7 strips of 32) ----------------
    for (int ks = 0; ks < 7; ++ks) {
        const int k0 = ks * 32;
        __syncthreads();   // x_s free (prev strip consumed)
        #pragma unroll
        for (int i = 0; i < 4; ++i) {
            const float* gp = xc + k0 * WW + (i * 448 + t) * 4;
            char* lp = (char*)x_s + (size_t)(i * 448 + t) * 16;
            __builtin_amdgcn_global_load_lds(
                (const __attribute__((address_space(1))) unsigned int*)gp,
                (__attribute__((address_space(3))) unsigned int*)lp, 16, 0, 0);
        }
        __syncthreads();   // x_s ready (compiler drains vmcnt before barrier)

        // A-frags: Lr from global (L2-resident, shared across all blocks)
        s16x8 af[7];
        #pragma unroll
        for (int pt = 0; pt < 7; ++pt) {
            int row = pt * 16 + lr16;
            af[pt] = *(const s16x8*)(lrbf + row * HH + k0 + 8 * g);
        }
        // B-frags: X[k][n] from LDS fp32, cvt->bf16, then MFMA column of 7 tiles
        #pragma unroll
        for (int nt = 0; nt < 2; ++nt) {
            const int col = 32 * w + 16 * nt + lr16;
            s16x8 bv;
            #pragma unroll
            for (int j = 0; j < 8; ++j)
                bv[j] = (short)f2bf(x_s[(8 * g + j) * WW + col]);
            #pragma unroll
            for (int pt = 0; pt < 7; ++pt)
                accA[pt][nt] = __builtin_amdgcn_mfma_f32_16x16x32_bf16(
                    af[pt], bv, accA[pt][nt], 0, 0, 0);
        }
        // rank-1 partial: s += (-1)^(j+k) X[2j+1][2k+1] over this strip
        #pragma unroll
        for (int i = 0; i < 4; ++i) {
            int e = t + 448 * i;               // 0..1791
            int jj = e / 112, kk = e % 112;    // jj<16 odd-row idx, kk odd-col idx
            float v = x_s[(2 * jj + 1) * WW + (2 * kk + 1)];
            spart += ((jj + kk) & 1) ? -v : v; // k0/2 is even, no extra sign
        }
    }

    // wave-reduce spart -> wsum[w]
    #pragma unroll
    for (int off = 32; off > 0; off >>= 1)
        spart += __shfl_down(spart, off, 64);
    if (l == 0) wsum[w] = spart;

    // write Y tiles to LDS as bf16 (C-layout: row = pt*16+4g+r, col per lane)
    #pragma unroll
    for (int pt = 0; pt < 7; ++pt) {
        #pragma unroll
        for (int nt = 0; nt < 2; ++nt) {
            const int col = 32 * w + 16 * nt + lr16;
            #pragma unroll
            for (int r = 0; r < 4; ++r) {
                int row = pt * 16 + 4 * g + r;
                y_s[row * YP + col] = f2bf(accA[pt][nt][r]);
            }
        }
    }
    __syncthreads();   // y_s + wsum ready

    // ---------------- Phase B: Out = Y * Lr^T  (K = n, 7 steps) ----------------
    f32x4 accB[7];
    #pragma unroll
    for (int i = 0; i < 7; ++i) accB[i] = f32x4{0.f, 0.f, 0.f, 0.f};

    for (int ks = 0; ks < 7; ++ks) {
        const int k0 = ks * 32;
        // B-frag: (Lr^T)[k][q] = Lr[q][k] -> row q contiguous k
        const int q = 16 * w + lr16;
        s16x8 bf = *(const s16x8*)(lrbf + q * HH + k0 + 8 * g);
        #pragma unroll
        for (int pt = 0; pt < 7; ++pt) {
            int row = pt * 16 + lr16;
            s16x8 yf = *(const s16x8*)(&y_s[row * YP + k0 + 8 * g]);
            accB[pt] = __builtin_amdgcn_mfma_f32_16x16x32_bf16(yf, bf, accB[pt], 0, 0, 0);
        }
    }

    // epilogue: rank-1 correction + store
    float ssum = 0.0f;
    #pragma unroll
    for (int i = 0; i < 7; ++i) ssum += wsum[i];
    const float s = ssum * (1.0f / (224.0f * 224.0f));

    float* __restrict__ oc = out + (size_t)c * (OH * OW);
    const int q = 16 * w + lr16;
    #pragma unroll
    for (int pt = 0; pt < 7; ++pt) {
        #pragma unroll
        for (int r = 0; r < 4; ++r) {
            int p = pt * 16 + 4 * g + r;
            oc[p * OW + q] = accB[pt][r] - (((p + q) & 1) ? -s : s);
        }
    }
}

extern "C" void kernel_launch(void* const* d_in, const int* in_sizes, int n_in,
                              void* d_out, int out_size, void* d_ws, size_t ws_size,
                              hipStream_t stream) {
    const float* x = (const float*)d_in[0];
    float* out = (float*)d_out;
    unsigned short* lrbf = (unsigned short*)d_ws;   // 112*224*2 = 50176 B

    hipLaunchKernelGGL(lr_init_kernel, dim3((OH * HH + 255) / 256), dim3(256), 0, stream, lrbf);
    hipLaunchKernelGGL(flc_mfma_kernel, dim3(NCH), dim3(448), 0, stream, x, lrbf, out);
}

// Round 4
// 311.760 us; speedup vs baseline: 2.2485x; 1.1657x over previous
//
#include <hip/hip_runtime.h>
#include <math.h>

#define HH 224
#define WW 224
#define OH 112
#define OW 112
#define NCH 1024
#define YP 232   // y_s pitch (bf16 elems): 16B-aligned rows, good bank spread

typedef __attribute__((ext_vector_type(8))) short s16x8;
typedef __attribute__((ext_vector_type(4))) float f32x4;

static __device__ __host__ __forceinline__ unsigned short f2bf(float f) {
    union { float f; unsigned int u; } v; v.f = f;
    unsigned int r = (v.u + 0x7FFFu + ((v.u >> 16) & 1u)) >> 16;  // RNE
    return (unsigned short)r;
}

// Lr bf16 ROW-major [p=112][m=224] (A-operand layout: row p, contiguous k=m)
__global__ void lr_init_kernel(unsigned short* __restrict__ lrbf) {
    int idx = blockIdx.x * blockDim.x + threadIdx.x;
    if (idx >= OH * HH) return;
    int p = idx / HH;
    int m = idx % HH;
    float val = 0.0f;
    if ((m & 1) == 0) {
        val = (m == 2 * p) ? 0.5f : 0.0f;
    } else {
        int j = m >> 1;
        int r = 2 * p - m;                       // odd
        float a = (float)M_PI * (float)r * (1.0f / 224.0f);
        float sg = ((p - j) & 1) ? 1.0f : -1.0f; // sigma = -(-1)^(p-j)
        val = sg * (cosf(a) / sinf(a)) * (1.0f / 224.0f);
    }
    lrbf[p * HH + m] = f2bf(val);
}

// __launch_bounds__(448, 2): 2 waves/EU floor -> VGPR cap 256 (no spill).
// Round-3's (448,4) forced 64 VGPRs -> 244 MB of scratch spill traffic.
__launch_bounds__(448, 2)
__global__ void flc_mfma_kernel(const float* __restrict__ x,
                                const unsigned short* __restrict__ lrbf,
                                float* __restrict__ out) {
    __shared__ float x_s[32 * WW];            // 28672 B, linear (global_load_lds dest)
    __shared__ unsigned short y_s[OH * YP];   // 51968 B
    __shared__ float wsum[7];

    const int c = blockIdx.x;
    const int t = threadIdx.x;
    const int w = t >> 6;      // wave 0..6
    const int l = t & 63;
    const int lr16 = l & 15;
    const int g = l >> 4;      // 0..3

    const float* __restrict__ xc = x + (size_t)c * (HH * WW);

    f32x4 accA[7][2];
    #pragma unroll
    for (int i = 0; i < 7; ++i) {
        accA[i][0] = f32x4{0.f, 0.f, 0.f, 0.f};
        accA[i][1] = f32x4{0.f, 0.f, 0.f, 0.f};
    }
    float spart = 0.0f;

    // ---------------- Phase A: Y = Lr * X  (K = m, 7 strips of 32) ----------------
    for (int ks = 0; ks < 7; ++ks) {
        const int k0 = ks * 32;
        __syncthreads();   // x_s free (prev strip consumed)
        #pragma unroll
        for (int i = 0; i < 4; ++i) {
            const float* gp = xc + k0 * WW + (i * 448 + t) * 4;
            char* lp = (char*)x_s + (size_t)(i * 448 + t) * 16;
            __builtin_amdgcn_global_load_lds(
                (const __attribute__((address_space(1))) unsigned int*)gp,
                (__attribute__((address_space(3))) unsigned int*)lp, 16, 0, 0);
        }
        __syncthreads();   // x_s ready (compiler drains vmcnt before barrier)

        // A-frags: Lr from global (L2-resident, shared across all blocks)
        s16x8 af[7];
        #pragma unroll
        for (int pt = 0; pt < 7; ++pt) {
            int row = pt * 16 + lr16;
            af[pt] = *(const s16x8*)(lrbf + row * HH + k0 + 8 * g);
        }
        // B-frags: X[k][n] from LDS fp32, cvt->bf16, then MFMA column of 7 tiles
        #pragma unroll
        for (int nt = 0; nt < 2; ++nt) {
            const int col = 32 * w + 16 * nt + lr16;
            s16x8 bv;
            #pragma unroll
            for (int j = 0; j < 8; ++j)
                bv[j] = (short)f2bf(x_s[(8 * g + j) * WW + col]);
            #pragma unroll
            for (int pt = 0; pt < 7; ++pt)
                accA[pt][nt] = __builtin_amdgcn_mfma_f32_16x16x32_bf16(
                    af[pt], bv, accA[pt][nt], 0, 0, 0);
        }
        // rank-1 partial: s += (-1)^(j+k) X[2j+1][2k+1] over this strip
        #pragma unroll
        for (int i = 0; i < 4; ++i) {
            int e = t + 448 * i;               // 0..1791
            int jj = e / 112, kk = e % 112;    // jj<16 odd-row idx, kk odd-col idx
            float v = x_s[(2 * jj + 1) * WW + (2 * kk + 1)];
            spart += ((jj + kk) & 1) ? -v : v; // k0/2 is even, no extra sign
        }
    }

    // wave-reduce spart -> wsum[w]
    #pragma unroll
    for (int off = 32; off > 0; off >>= 1)
        spart += __shfl_down(spart, off, 64);
    if (l == 0) wsum[w] = spart;

    // write Y tiles to LDS as bf16 (C-layout: row = pt*16+4g+r, col per lane)
    #pragma unroll
    for (int pt = 0; pt < 7; ++pt) {
        #pragma unroll
        for (int nt = 0; nt < 2; ++nt) {
            const int col = 32 * w + 16 * nt + lr16;
            #pragma unroll
            for (int r = 0; r < 4; ++r) {
                int row = pt * 16 + 4 * g + r;
                y_s[row * YP + col] = f2bf(accA[pt][nt][r]);
            }
        }
    }
    __syncthreads();   // y_s + wsum ready

    // ---------------- Phase B: Out = Y * Lr^T  (K = n, 7 steps) ----------------
    f32x4 accB[7];
    #pragma unroll
    for (int i = 0; i < 7; ++i) accB[i] = f32x4{0.f, 0.f, 0.f, 0.f};

    for (int ks = 0; ks < 7; ++ks) {
        const int k0 = ks * 32;
        // B-frag: (Lr^T)[k][q] = Lr[q][k] -> row q contiguous k
        const int q = 16 * w + lr16;
        s16x8 bf = *(const s16x8*)(lrbf + q * HH + k0 + 8 * g);
        #pragma unroll
        for (int pt = 0; pt < 7; ++pt) {
            int row = pt * 16 + lr16;
            s16x8 yf = *(const s16x8*)(&y_s[row * YP + k0 + 8 * g]);
            accB[pt] = __builtin_amdgcn_mfma_f32_16x16x32_bf16(yf, bf, accB[pt], 0, 0, 0);
        }
    }

    // epilogue: rank-1 correction + store
    float ssum = 0.0f;
    #pragma unroll
    for (int i = 0; i < 7; ++i) ssum += wsum[i];
    const float s = ssum * (1.0f / (224.0f * 224.0f));

    float* __restrict__ oc = out + (size_t)c * (OH * OW);
    const int q = 16 * w + lr16;
    #pragma unroll
    for (int pt = 0; pt < 7; ++pt) {
        #pragma unroll
        for (int r = 0; r < 4; ++r) {
            int p = pt * 16 + 4 * g + r;
            oc[p * OW + q] = accB[pt][r] - (((p + q) & 1) ? -s : s);
        }
    }
}

extern "C" void kernel_launch(void* const* d_in, const int* in_sizes, int n_in,
                              void* d_out, int out_size, void* d_ws, size_t ws_size,
                              hipStream_t stream) {
    const float* x = (const float*)d_in[0];
    float* out = (float*)d_out;
    unsigned short* lrbf = (unsigned short*)d_ws;   // 112*224*2 = 50176 B

    hipLaunchKernelGGL(lr_init_kernel, dim3((OH * HH + 255) / 256), dim3(256), 0, stream, lrbf);
    hipLaunchKernelGGL(flc_mfma_kernel, dim3(NCH), dim3(448), 0, stream, x, lrbf, out);
}